// Round 8
// baseline (59.707 us; speedup 1.0000x reference)
//
#include <hip/hip_runtime.h>

// CCAMDec: out = x + scale * softmax(max_k(E)-E) @ y,  E = x·yᵀ over HW
// N=8, C=512, K=64, HW=4096. softmax(max-E) == softmax(-E) (shift invariance).
#define N_ 8
#define C_ 512
#define K_ 64
#define HW_ 4096
#define SPLITS 4
#define SRANGE (HW_ / SPLITS)   // 1024 s per k_energy block
#define SCHUNK 128              // s per staged chunk
#define NCH 8                   // chunks per block

typedef __attribute__((ext_vector_type(8))) short short8;   // 8 bf16 (4 VGPRs) MFMA A/B frag
typedef __attribute__((ext_vector_type(4))) float floatx4;  // MFMA C/D frag

// 8 f32 -> 8 bf16 via hardware v_cvt_pk_bf16_f32 (RNE, 1 instr / 2 elems)
__device__ __forceinline__ short8 cvt8(const float* __restrict__ p){
  float4 u = *(const float4*)p;
  float4 w = *(const float4*)(p + 4);
  union { unsigned u32[4]; short8 s; } r;
  asm("v_cvt_pk_bf16_f32 %0, %1, %2" : "=v"(r.u32[0]) : "v"(u.x), "v"(u.y));
  asm("v_cvt_pk_bf16_f32 %0, %1, %2" : "=v"(r.u32[1]) : "v"(u.z), "v"(u.w));
  asm("v_cvt_pk_bf16_f32 %0, %1, %2" : "=v"(r.u32[2]) : "v"(w.x), "v"(w.y));
  asm("v_cvt_pk_bf16_f32 %0, %1, %2" : "=v"(r.u32[3]) : "v"(w.z), "v"(w.w));
  return r.s;
}

// async global -> LDS, 16 B/lane (1 KB/wave), zero VGPR cost
__device__ __forceinline__ void gload16(const void* g, void* l){
  __builtin_amdgcn_global_load_lds(
      (const __attribute__((address_space(1))) void*)g,
      (__attribute__((address_space(3))) void*)l, 16, 0, 0);
}

// K0: y (f32, [n][k][s]) -> ybf (bf16 row-major [n][k][s]) and ytr (bf16 [n][s][k])
__global__ __launch_bounds__(256) void k_prep(const float* __restrict__ y,
                                              unsigned short* __restrict__ ybf,
                                              unsigned short* __restrict__ ytr){
  __shared__ unsigned short tile[64][72];
  int n  = blockIdx.x >> 6;                 // 64 s-tiles per batch
  int s0 = (blockIdx.x & 63) << 6;
  int tid = threadIdx.x;
  int k  = tid >> 2;
  int sc = (tid & 3) << 4;
  const float* yp = y + ((size_t)n * K_ + k) * HW_ + s0 + sc;
  union { unsigned short u16[16]; short8 s8[2]; uint4 q[2]; } u;
  u.s8[0] = cvt8(yp);
  u.s8[1] = cvt8(yp + 8);
  unsigned short* rp = ybf + ((size_t)n * K_ + k) * HW_ + s0 + sc;
  *(uint4*)rp       = u.q[0];
  *(uint4*)(rp + 8) = u.q[1];
#pragma unroll
  for (int j = 0; j < 16; ++j) tile[sc + j][k] = u.u16[j];
  __syncthreads();
  int s  = tid >> 2;
  int kc = (tid & 3) << 4;
  unsigned short* tp = ytr + ((size_t)n * HW_ + s0 + s) * K_ + kc;
  *(uint4*)tp       = *(const uint4*)&tile[s][kc];
  *(uint4*)(tp + 8) = *(const uint4*)&tile[s][kc + 8];
}

// K1: partial energies.  Block = (n, 16c, 1024s), 4 waves.  8 chunks of 128s,
// DOUBLE-BUFFERED LDS + counted vmcnt (T3/T4): chunk ch+1's 6 gload_lds stay
// in flight across chunk ch's compute; raw s_barrier (no vmcnt-0 drain).
// Source-side XOR pre-swizzle ^((row&7)<<4), same XOR on ds_read (rule #21).
__global__ __launch_bounds__(256) void k_energy(const float* __restrict__ x,
                                                const unsigned short* __restrict__ ybf,
                                                float* __restrict__ partial){
  __shared__ char As[2][16 * 512];   // 2 x 8 KB:  16 c-rows x 128 f32
  __shared__ char Bs[2][64 * 256];   // 2 x 16 KB: 64 k-rows x 128 bf16
  const int bid = blockIdx.x;        // 8n * 32ct * 4sp = 1024
  const int sp = bid & 3;
  const int ct = (bid >> 2) & 31;
  const int n  = bid >> 7;
  const int tid = threadIdx.x;
  const int w = tid >> 6, l = tid & 63;
  const int lo = l & 15, hi = l >> 4;
  const int c0 = ct << 4;
  const int sb = sp * SRANGE;

  // chunk-invariant per-lane source addresses (bytes)
  const int ar0 = ((w << 1) + 0) * 2 + (l >> 5);
  const int ar1 = ((w << 1) + 1) * 2 + (l >> 5);
  const char* asrc0 = (const char*)(x + ((size_t)n * C_ + c0 + ar0) * HW_ + sb)
                      + ((16 * (l & 31)) ^ ((ar0 & 7) << 4));
  const char* asrc1 = (const char*)(x + ((size_t)n * C_ + c0 + ar1) * HW_ + sb)
                      + ((16 * (l & 31)) ^ ((ar1 & 7) << 4));
  const char* bsrc[4];
#pragma unroll
  for (int j = 0; j < 4; ++j){
    int kk = ((w << 2) + j) * 4 + (l >> 4);
    bsrc[j] = (const char*)(ybf + ((size_t)n * K_ + kk) * HW_ + sb)
              + ((16 * (l & 15)) ^ ((kk & 7) << 4));
  }

  floatx4 acc = {0.f, 0.f, 0.f, 0.f};
  const int kk_r = (w << 4) + lo;                    // compute-side B row
  const int bswz = (kk_r & 7) << 4;
  const int aswz = (lo & 7) << 4;

#define STAGE(BUF, CH)                                                         \
  {                                                                            \
    gload16(asrc0 + (size_t)(CH) * (SCHUNK * 4), As[BUF] + ((w << 1) + 0) * 1024); \
    gload16(asrc1 + (size_t)(CH) * (SCHUNK * 4), As[BUF] + ((w << 1) + 1) * 1024); \
    _Pragma("unroll")                                                          \
    for (int j = 0; j < 4; ++j)                                                \
      gload16(bsrc[j] + (size_t)(CH) * (SCHUNK * 2), Bs[BUF] + ((w << 2) + j) * 1024); \
  }

  STAGE(0, 0)                       // prologue: chunk 0 in flight (6/wave)

#pragma unroll
  for (int ch = 0; ch < NCH; ++ch){
    const int cur = ch & 1;
    if (ch + 1 < NCH){
      STAGE(cur ^ 1, ch + 1)        // 6 more in flight (<=12)
      asm volatile("s_waitcnt vmcnt(6)" ::: "memory");   // chunk ch complete
    } else {
      asm volatile("s_waitcnt vmcnt(0)" ::: "memory");
    }
    __builtin_amdgcn_s_barrier();   // all waves' cur-chunk data in LDS
    __builtin_amdgcn_sched_barrier(0);
#pragma unroll
    for (int ss = 0; ss < 4; ++ss){
      int aoff = ss * 128 + hi * 32;
      const char* ab = As[cur] + lo * 512;
      float4 a0f = *(const float4*)(ab + ((aoff     ) ^ aswz));
      float4 a1f = *(const float4*)(ab + ((aoff + 16) ^ aswz));
      union { unsigned u32[4]; short8 s; } af;
      asm("v_cvt_pk_bf16_f32 %0, %1, %2" : "=v"(af.u32[0]) : "v"(a0f.x), "v"(a0f.y));
      asm("v_cvt_pk_bf16_f32 %0, %1, %2" : "=v"(af.u32[1]) : "v"(a0f.z), "v"(a0f.w));
      asm("v_cvt_pk_bf16_f32 %0, %1, %2" : "=v"(af.u32[2]) : "v"(a1f.x), "v"(a1f.y));
      asm("v_cvt_pk_bf16_f32 %0, %1, %2" : "=v"(af.u32[3]) : "v"(a1f.z), "v"(a1f.w));
      short8 b = *(const short8*)(Bs[cur] + kk_r * 256 + ((ss * 64 + hi * 16) ^ bswz));
      acc = __builtin_amdgcn_mfma_f32_16x16x32_bf16(af.s, b, acc, 0, 0, 0);
    }
    __builtin_amdgcn_sched_barrier(0);   // pin ds_read/MFMA above the barrier
    __builtin_amdgcn_s_barrier();        // cur buffer free for overwrite
  }
#undef STAGE

  // D layout: col = lo -> k = 16w+lo, row = hi*4+r -> c  [m89-verified]
  float* pp = partial + (((size_t)sp * N_ + n) * C_ + c0) * K_;
#pragma unroll
  for (int r = 0; r < 4; ++r)
    pp[(size_t)(hi * 4 + r) * K_ + kk_r] = acc[r];
}

// K2: out = x + scale * softmax(-E) @ y, softmax fused into the prologue:
// each block reduces partial over splits for its 16 c-rows (L2-hot, 16 KB),
// softmax in-block, att tile in XOR-swizzled LDS (bf16).  Main loop as before:
// 4 waves, 16c x 512s, acc transposed through LDS -> float4 x-load + store.
__global__ __launch_bounds__(256) void k_out(const float* __restrict__ x,
                                             const float* __restrict__ partial,
                                             const unsigned short* __restrict__ ytr,
                                             const float* __restrict__ scale,
                                             float* __restrict__ out){
  __shared__ float xt[4][16][36];   // per-wave 16x32 transpose buffer
  __shared__ char attl[16 * 128];   // 16 c-rows x 64 k bf16, XOR-swizzled
  int bid = blockIdx.x;             // 8n * 32ct * 8sb = 2048
  int sb = bid & 7;
  int ct = (bid >> 3) & 31;
  int n  = bid >> 8;
  int tid = threadIdx.x;
  int w  = tid >> 6;
  int l  = tid & 63, lo = l & 15, hi = l >> 4;
  int c0 = ct << 4;
  int s0 = (sb << 9) + (w << 7);    // 512 per block, 128 per wave
  float sc = scale[0];

  // ---- fused softmax prologue: thread -> (c = tid>>4, 4 k's at 4*(tid&15)) ----
  {
    int c = tid >> 4, j = tid & 15;
    const float* pp = partial + ((size_t)n * C_ + c0 + c) * K_ + 4 * j;
    float e0 = 0.f, e1 = 0.f, e2 = 0.f, e3 = 0.f;
#pragma unroll
    for (int sp = 0; sp < SPLITS; ++sp){
      float4 t = *(const float4*)(pp + (size_t)sp * (N_ * C_ * K_));
      e0 += t.x; e1 += t.y; e2 += t.z; e3 += t.w;
    }
    float m = fminf(fminf(e0, e1), fminf(e2, e3));
#pragma unroll
    for (int off = 8; off; off >>= 1) m = fminf(m, __shfl_xor(m, off, 16));
    float p0 = __expf(m - e0), p1 = __expf(m - e1);
    float p2 = __expf(m - e2), p3 = __expf(m - e3);
    float s = p0 + p1 + p2 + p3;
#pragma unroll
    for (int off = 8; off; off >>= 1) s += __shfl_xor(s, off, 16);
    float inv = 1.f / s;
    unsigned d0, d1;
    asm("v_cvt_pk_bf16_f32 %0, %1, %2" : "=v"(d0) : "v"(p0 * inv), "v"(p1 * inv));
    asm("v_cvt_pk_bf16_f32 %0, %1, %2" : "=v"(d1) : "v"(p2 * inv), "v"(p3 * inv));
    uint2 dd; dd.x = d0; dd.y = d1;
    *(uint2*)(attl + c * 128 + ((8 * j) ^ ((c & 7) << 4))) = dd;
  }
  __syncthreads();

  short8 a0 = *(const short8*)(attl + lo * 128 + (((     hi * 16)) ^ ((lo & 7) << 4)));
  short8 a1 = *(const short8*)(attl + lo * 128 + (((64 + hi * 16)) ^ ((lo & 7) << 4)));

  const unsigned short* bp0 = ytr + ((size_t)n * HW_ + s0 + lo) * K_ + hi * 8;
  int row = l >> 2, c8 = (l & 3) << 3;     // epilogue: lane -> (row, 8 cols)
  size_t eoff = ((size_t)n * C_ + c0 + row) * HW_ + s0 + c8;
  const float* xp = x   + eoff;
  float*       op = out + eoff;
  float (*T)[36] = xt[w];

#pragma unroll
  for (int p = 0; p < 4; ++p){
    const unsigned short* bp = bp0 + (size_t)(p * 32) * K_;
    short8 b0 = *(const short8*)(bp);
    short8 b1 = *(const short8*)(bp + 32);
    short8 b2 = *(const short8*)(bp + 16 * K_);
    short8 b3 = *(const short8*)(bp + 16 * K_ + 32);
    floatx4 acc0 = {0.f,0.f,0.f,0.f};
    floatx4 acc1 = {0.f,0.f,0.f,0.f};
    acc0 = __builtin_amdgcn_mfma_f32_16x16x32_bf16(a0, b0, acc0, 0, 0, 0);
    acc0 = __builtin_amdgcn_mfma_f32_16x16x32_bf16(a1, b1, acc0, 0, 0, 0);
    acc1 = __builtin_amdgcn_mfma_f32_16x16x32_bf16(a0, b2, acc1, 0, 0, 0);
    acc1 = __builtin_amdgcn_mfma_f32_16x16x32_bf16(a1, b3, acc1, 0, 0, 0);
    // acc layout: row = hi*4+r, col = lo (acc0: s+0..15, acc1: s+16..31)
#pragma unroll
    for (int r = 0; r < 4; ++r){
      T[hi * 4 + r][lo]      = acc0[r];
      T[hi * 4 + r][16 + lo] = acc1[r];
    }
    float4 v0 = *(const float4*)&T[row][c8];       // in-wave DS ordering
    float4 v1 = *(const float4*)&T[row][c8 + 4];
    float4 u0 = *(const float4*)(xp + p * 32);
    float4 u1 = *(const float4*)(xp + p * 32 + 4);
    float4 o0, o1;
    o0.x = u0.x + sc * v0.x; o0.y = u0.y + sc * v0.y;
    o0.z = u0.z + sc * v0.z; o0.w = u0.w + sc * v0.w;
    o1.x = u1.x + sc * v1.x; o1.y = u1.y + sc * v1.y;
    o1.z = u1.z + sc * v1.z; o1.w = u1.w + sc * v1.w;
    *(float4*)(op + p * 32)     = o0;
    *(float4*)(op + p * 32 + 4) = o1;
  }
}

extern "C" void kernel_launch(void* const* d_in, const int* in_sizes, int n_in,
                              void* d_out, int out_size, void* d_ws, size_t ws_size,
                              hipStream_t stream){
  const float* x     = (const float*)d_in[0];
  const float* y     = (const float*)d_in[1];
  const float* scale = (const float*)d_in[2];
  float* out = (float*)d_out;

  // ws layout (12 MiB total):
  //   partial : SPLITS * N*C*K f32  = 4 MiB  @ 0
  //   ybf     : N*K*HW bf16         = 4 MiB  @ 4 MiB
  //   ytr     : N*HW*K bf16         = 4 MiB  @ 8 MiB
  char* ws = (char*)d_ws;
  float*          partial = (float*)(ws);
  unsigned short* ybf     = (unsigned short*)(ws + (4u<<20));
  unsigned short* ytr     = (unsigned short*)(ws + (8u<<20));

  k_prep   <<<N_ * (HW_/64),    256, 0, stream>>>(y, ybf, ytr);
  k_energy <<<N_ * 32 * SPLITS, 256, 0, stream>>>(x, ybf, partial);
  k_out    <<<N_ * 32 * 8,      256, 0, stream>>>(x, partial, ytr, scale, out);
}

// Round 9
// 58.950 us; speedup vs baseline: 1.0128x; 1.0128x over previous
//
#include <hip/hip_runtime.h>

// CCAMDec: out = x + scale * softmax(max_k(E)-E) @ y,  E = x·yᵀ over HW
// N=8, C=512, K=64, HW=4096. softmax(max-E) == softmax(-E) (shift invariance).
#define N_ 8
#define C_ 512
#define K_ 64
#define HW_ 4096
#define SPLITS 4
#define SRANGE (HW_ / SPLITS)   // 1024 s per k_energy block
#define SCHUNK 128              // s per staged chunk
#define NCH 8                   // chunks per block

typedef __attribute__((ext_vector_type(8))) short short8;   // 8 bf16 (4 VGPRs) MFMA A/B frag
typedef __attribute__((ext_vector_type(4))) float floatx4;  // MFMA C/D frag

// 8 f32 -> 8 bf16 via hardware v_cvt_pk_bf16_f32 (RNE, 1 instr / 2 elems)
__device__ __forceinline__ short8 cvt8(const float* __restrict__ p){
  float4 u = *(const float4*)p;
  float4 w = *(const float4*)(p + 4);
  union { unsigned u32[4]; short8 s; } r;
  asm("v_cvt_pk_bf16_f32 %0, %1, %2" : "=v"(r.u32[0]) : "v"(u.x), "v"(u.y));
  asm("v_cvt_pk_bf16_f32 %0, %1, %2" : "=v"(r.u32[1]) : "v"(u.z), "v"(u.w));
  asm("v_cvt_pk_bf16_f32 %0, %1, %2" : "=v"(r.u32[2]) : "v"(w.x), "v"(w.y));
  asm("v_cvt_pk_bf16_f32 %0, %1, %2" : "=v"(r.u32[3]) : "v"(w.z), "v"(w.w));
  return r.s;
}

// async global -> LDS, 16 B/lane (1 KB/wave), zero VGPR cost
__device__ __forceinline__ void gload16(const void* g, void* l){
  __builtin_amdgcn_global_load_lds(
      (const __attribute__((address_space(1))) void*)g,
      (__attribute__((address_space(3))) void*)l, 16, 0, 0);
}

// K0: y (f32, [n][k][s]) -> ybf (bf16 row-major [n][k][s]) and ytr (bf16 [n][s][k])
__global__ __launch_bounds__(256) void k_prep(const float* __restrict__ y,
                                              unsigned short* __restrict__ ybf,
                                              unsigned short* __restrict__ ytr){
  __shared__ unsigned short tile[64][72];
  int n  = blockIdx.x >> 6;                 // 64 s-tiles per batch
  int s0 = (blockIdx.x & 63) << 6;
  int tid = threadIdx.x;
  int k  = tid >> 2;
  int sc = (tid & 3) << 4;
  const float* yp = y + ((size_t)n * K_ + k) * HW_ + s0 + sc;
  union { unsigned short u16[16]; short8 s8[2]; uint4 q[2]; } u;
  u.s8[0] = cvt8(yp);
  u.s8[1] = cvt8(yp + 8);
  unsigned short* rp = ybf + ((size_t)n * K_ + k) * HW_ + s0 + sc;
  *(uint4*)rp       = u.q[0];
  *(uint4*)(rp + 8) = u.q[1];
#pragma unroll
  for (int j = 0; j < 16; ++j) tile[sc + j][k] = u.u16[j];
  __syncthreads();
  int s  = tid >> 2;
  int kc = (tid & 3) << 4;
  unsigned short* tp = ytr + ((size_t)n * HW_ + s0 + s) * K_ + kc;
  *(uint4*)tp       = *(const uint4*)&tile[s][kc];
  *(uint4*)(tp + 8) = *(const uint4*)&tile[s][kc + 8];
}

// K1: partial energies.  Block = (n, 16c, 1024s), 4 waves, 8 chunks of 128s,
// double-buffered LDS + counted vmcnt; gload_lds width-16 staging only.
// Operand-swapped MFMA: A = y-frag (M=k), B = x-frag (N=c) ->
// D row = k (4 consecutive per lane) -> one float4 partial-store.
// partial layout: [sp][n][c][k].
__global__ __launch_bounds__(256) void k_energy(const float* __restrict__ x,
                                                const unsigned short* __restrict__ ybf,
                                                float* __restrict__ partial){
  __shared__ char As[2][16 * 512];   // 2 x 8 KB:  16 c-rows x 128 f32
  __shared__ char Bs[2][64 * 256];   // 2 x 16 KB: 64 k-rows x 128 bf16
  const int bid = ((blockIdx.x & 7) << 7) | (blockIdx.x >> 3);  // XCD swizzle (1024%8==0)
  const int sp = bid & 3;
  const int ct = (bid >> 2) & 31;
  const int n  = bid >> 7;
  const int tid = threadIdx.x;
  const int w = tid >> 6, l = tid & 63;
  const int lo = l & 15, hi = l >> 4;
  const int c0 = ct << 4;
  const int sb = sp * SRANGE;

  // chunk-invariant per-lane source addresses (bytes)
  const int ar0 = ((w << 1) + 0) * 2 + (l >> 5);
  const int ar1 = ((w << 1) + 1) * 2 + (l >> 5);
  const char* asrc0 = (const char*)(x + ((size_t)n * C_ + c0 + ar0) * HW_ + sb)
                      + ((16 * (l & 31)) ^ ((ar0 & 7) << 4));
  const char* asrc1 = (const char*)(x + ((size_t)n * C_ + c0 + ar1) * HW_ + sb)
                      + ((16 * (l & 31)) ^ ((ar1 & 7) << 4));
  const char* bsrc[4];
#pragma unroll
  for (int j = 0; j < 4; ++j){
    int kk = ((w << 2) + j) * 4 + (l >> 4);
    bsrc[j] = (const char*)(ybf + ((size_t)n * K_ + kk) * HW_ + sb)
              + ((16 * (l & 15)) ^ ((kk & 7) << 4));
  }

  floatx4 acc = {0.f, 0.f, 0.f, 0.f};
  const int kk_r = (w << 4) + lo;                    // y-frag row (A operand, M=k)
  const int bswz = (kk_r & 7) << 4;
  const int aswz = (lo & 7) << 4;

#define STAGE(BUF, CH)                                                         \
  {                                                                            \
    gload16(asrc0 + (size_t)(CH) * (SCHUNK * 4), As[BUF] + ((w << 1) + 0) * 1024); \
    gload16(asrc1 + (size_t)(CH) * (SCHUNK * 4), As[BUF] + ((w << 1) + 1) * 1024); \
    _Pragma("unroll")                                                          \
    for (int j = 0; j < 4; ++j)                                                \
      gload16(bsrc[j] + (size_t)(CH) * (SCHUNK * 2), Bs[BUF] + ((w << 2) + j) * 1024); \
  }

  STAGE(0, 0)                       // prologue: chunk 0 in flight (6/wave)

#pragma unroll
  for (int ch = 0; ch < NCH; ++ch){
    const int cur = ch & 1;
    if (ch + 1 < NCH){
      STAGE(cur ^ 1, ch + 1)        // 6 more in flight (<=12)
      asm volatile("s_waitcnt vmcnt(6)" ::: "memory");   // chunk ch complete
    } else {
      asm volatile("s_waitcnt vmcnt(0)" ::: "memory");
    }
    __builtin_amdgcn_s_barrier();   // all waves' cur-chunk data in LDS
    __builtin_amdgcn_sched_barrier(0);
#pragma unroll
    for (int ss = 0; ss < 4; ++ss){
      int aoff = ss * 128 + hi * 32;
      const char* ab = As[cur] + lo * 512;
      float4 a0f = *(const float4*)(ab + ((aoff     ) ^ aswz));
      float4 a1f = *(const float4*)(ab + ((aoff + 16) ^ aswz));
      union { unsigned u32[4]; short8 s; } af;
      asm("v_cvt_pk_bf16_f32 %0, %1, %2" : "=v"(af.u32[0]) : "v"(a0f.x), "v"(a0f.y));
      asm("v_cvt_pk_bf16_f32 %0, %1, %2" : "=v"(af.u32[1]) : "v"(a0f.z), "v"(a0f.w));
      asm("v_cvt_pk_bf16_f32 %0, %1, %2" : "=v"(af.u32[2]) : "v"(a1f.x), "v"(a1f.y));
      asm("v_cvt_pk_bf16_f32 %0, %1, %2" : "=v"(af.u32[3]) : "v"(a1f.z), "v"(a1f.w));
      short8 b = *(const short8*)(Bs[cur] + kk_r * 256 + ((ss * 64 + hi * 16) ^ bswz));
      // swapped: A = y-frag (M=k), B = x-frag (N=c)
      acc = __builtin_amdgcn_mfma_f32_16x16x32_bf16(b, af.s, acc, 0, 0, 0);
    }
    __builtin_amdgcn_sched_barrier(0);   // pin ds_read/MFMA above the barrier
    __builtin_amdgcn_s_barrier();        // cur buffer free for overwrite
  }
#undef STAGE

  // D: col = lo -> c = c0+lo ; row = hi*4+r -> k = w*16 + hi*4 + r
  float* pp = partial + (((size_t)sp * N_ + n) * C_ + c0 + lo) * K_ + (w << 4) + (hi << 2);
  *(floatx4*)pp = acc;
}

// K2: out = x + scale * softmax(-E) @ y.  Softmax fused in prologue (att tile
// in XOR-swizzled LDS).  Main loop operand-swapped: D = ytr_tile(M=s) x att^T
// (N=c) -> lane owns out[c0+lo][s+hi*4..+4) = native float4 load/store,
// NO LDS transpose.  Per wave: 8 s-tiles x {2 ytr loads, 1 x load, 2 MFMA,
// 1 store}.  4 waves/block, 16c x 512s per block.
__global__ __launch_bounds__(256) void k_out(const float* __restrict__ x,
                                             const float* __restrict__ partial,
                                             const unsigned short* __restrict__ ytr,
                                             const float* __restrict__ scale,
                                             float* __restrict__ out){
  __shared__ char attl[16 * 128];   // 16 c-rows x 64 k bf16, XOR-swizzled
  int bid = ((blockIdx.x & 7) << 8) | (blockIdx.x >> 3);  // XCD swizzle (2048%8==0)
  int sb = bid & 7;
  int ct = (bid >> 3) & 31;
  int n  = bid >> 8;
  int tid = threadIdx.x;
  int w  = tid >> 6;
  int l  = tid & 63, lo = l & 15, hi = l >> 4;
  int c0 = ct << 4;
  int s0 = (sb << 9) + (w << 7);    // 512 per block, 128 per wave
  float sc = scale[0];

  // ---- fused softmax prologue: thread -> (c = tid>>4, 4 k's at 4*(tid&15)) ----
  {
    int c = tid >> 4, j = tid & 15;
    const float* pp = partial + ((size_t)n * C_ + c0 + c) * K_ + 4 * j;
    float e0 = 0.f, e1 = 0.f, e2 = 0.f, e3 = 0.f;
#pragma unroll
    for (int sp = 0; sp < SPLITS; ++sp){
      float4 t = *(const float4*)(pp + (size_t)sp * (N_ * C_ * K_));
      e0 += t.x; e1 += t.y; e2 += t.z; e3 += t.w;
    }
    float m = fminf(fminf(e0, e1), fminf(e2, e3));
#pragma unroll
    for (int off = 8; off; off >>= 1) m = fminf(m, __shfl_xor(m, off, 16));
    float p0 = __expf(m - e0), p1 = __expf(m - e1);
    float p2 = __expf(m - e2), p3 = __expf(m - e3);
    float s = p0 + p1 + p2 + p3;
#pragma unroll
    for (int off = 8; off; off >>= 1) s += __shfl_xor(s, off, 16);
    float inv = 1.f / s;
    unsigned d0, d1;
    asm("v_cvt_pk_bf16_f32 %0, %1, %2" : "=v"(d0) : "v"(p0 * inv), "v"(p1 * inv));
    asm("v_cvt_pk_bf16_f32 %0, %1, %2" : "=v"(d1) : "v"(p2 * inv), "v"(p3 * inv));
    uint2 dd; dd.x = d0; dd.y = d1;
    *(uint2*)(attl + c * 128 + ((8 * j) ^ ((c & 7) << 4))) = dd;
  }
  __syncthreads();

  // att fragments (B operand: col = lo -> c, per-lane k = hi*8.. / +32)
  short8 batt0 = *(const short8*)(attl + lo * 128 + ((     hi * 16) ^ ((lo & 7) << 4)));
  short8 batt1 = *(const short8*)(attl + lo * 128 + ((64 + hi * 16) ^ ((lo & 7) << 4)));

  const unsigned short* yb = ytr + (size_t)n * HW_ * K_;
  const size_t obase = ((size_t)n * C_ + c0 + lo) * HW_ + s0 + (hi << 2);

#pragma unroll
  for (int st = 0; st < 8; ++st){
    const unsigned short* ap = yb + (size_t)(s0 + st * 16 + lo) * K_ + hi * 8;
    short8 a0 = *(const short8*)(ap);        // A operand: row = lo -> s, k = hi*8..
    short8 a1 = *(const short8*)(ap + 32);   // k = 32 + hi*8..
    floatx4 acc = {0.f, 0.f, 0.f, 0.f};
    acc = __builtin_amdgcn_mfma_f32_16x16x32_bf16(a0, batt0, acc, 0, 0, 0);
    acc = __builtin_amdgcn_mfma_f32_16x16x32_bf16(a1, batt1, acc, 0, 0, 0);
    // D: col = lo -> c, row = hi*4+r -> s = s0 + st*16 + hi*4 + r
    size_t off = obase + st * 16;
    float4 xv = *(const float4*)(x + off);
    float4 o;
    o.x = xv.x + sc * acc[0]; o.y = xv.y + sc * acc[1];
    o.z = xv.z + sc * acc[2]; o.w = xv.w + sc * acc[3];
    *(float4*)(out + off) = o;
  }
}

extern "C" void kernel_launch(void* const* d_in, const int* in_sizes, int n_in,
                              void* d_out, int out_size, void* d_ws, size_t ws_size,
                              hipStream_t stream){
  const float* x     = (const float*)d_in[0];
  const float* y     = (const float*)d_in[1];
  const float* scale = (const float*)d_in[2];
  float* out = (float*)d_out;

  // ws layout (12 MiB total):
  //   partial : SPLITS * N*C*K f32  = 4 MiB  @ 0   ([sp][n][c][k])
  //   ybf     : N*K*HW bf16         = 4 MiB  @ 4 MiB
  //   ytr     : N*HW*K bf16         = 4 MiB  @ 8 MiB
  char* ws = (char*)d_ws;
  float*          partial = (float*)(ws);
  unsigned short* ybf     = (unsigned short*)(ws + (4u<<20));
  unsigned short* ytr     = (unsigned short*)(ws + (8u<<20));

  k_prep   <<<N_ * (HW_/64),    256, 0, stream>>>(y, ybf, ytr);
  k_energy <<<N_ * 32 * SPLITS, 256, 0, stream>>>(x, ybf, partial);
  k_out    <<<N_ * 32 * 8,      256, 0, stream>>>(x, partial, ytr, scale, out);
}

// Round 10
// 54.541 us; speedup vs baseline: 1.0947x; 1.0808x over previous
//
#include <hip/hip_runtime.h>

// CCAMDec: out = x + scale * softmax(max_k(E)-E) @ y,  E = x·yᵀ over HW
// N=8, C=512, K=64, HW=4096. softmax(max-E) == softmax(-E) (shift invariance).
#define N_ 8
#define C_ 512
#define K_ 64
#define HW_ 4096
#define SPLITS 4                // s-splits at block level in k_energy
#define NSPL (SPLITS * 4)       // total partial splits (x4 waves)
#define SRANGE (HW_ / SPLITS)   // 1024 s per k_energy block
#define SCHUNK 128              // s per staged chunk
#define NCH 8                   // chunks per block

typedef __attribute__((ext_vector_type(8))) short short8;   // 8 bf16 (4 VGPRs) MFMA A/B frag
typedef __attribute__((ext_vector_type(4))) float floatx4;  // MFMA C/D frag

// 8 f32 -> 8 bf16 via hardware v_cvt_pk_bf16_f32 (RNE, 1 instr / 2 elems)
__device__ __forceinline__ short8 cvt8(const float* __restrict__ p){
  float4 u = *(const float4*)p;
  float4 w = *(const float4*)(p + 4);
  union { unsigned u32[4]; short8 s; } r;
  asm("v_cvt_pk_bf16_f32 %0, %1, %2" : "=v"(r.u32[0]) : "v"(u.x), "v"(u.y));
  asm("v_cvt_pk_bf16_f32 %0, %1, %2" : "=v"(r.u32[1]) : "v"(u.z), "v"(u.w));
  asm("v_cvt_pk_bf16_f32 %0, %1, %2" : "=v"(r.u32[2]) : "v"(w.x), "v"(w.y));
  asm("v_cvt_pk_bf16_f32 %0, %1, %2" : "=v"(r.u32[3]) : "v"(w.z), "v"(w.w));
  return r.s;
}

// async global -> LDS, 16 B/lane (1 KB/wave), zero VGPR cost
__device__ __forceinline__ void gload16(const void* g, void* l){
  __builtin_amdgcn_global_load_lds(
      (const __attribute__((address_space(1))) void*)g,
      (__attribute__((address_space(3))) void*)l, 16, 0, 0);
}

// K0: y (f32, [n][k][s]) -> ybf (bf16 row-major [n][k][s]) and ytr (bf16 [n][s][k])
__global__ __launch_bounds__(256) void k_prep(const float* __restrict__ y,
                                              unsigned short* __restrict__ ybf,
                                              unsigned short* __restrict__ ytr){
  __shared__ unsigned short tile[64][72];
  int n  = blockIdx.x >> 6;                 // 64 s-tiles per batch
  int s0 = (blockIdx.x & 63) << 6;
  int tid = threadIdx.x;
  int k  = tid >> 2;
  int sc = (tid & 3) << 4;
  const float* yp = y + ((size_t)n * K_ + k) * HW_ + s0 + sc;
  union { unsigned short u16[16]; short8 s8[2]; uint4 q[2]; } u;
  u.s8[0] = cvt8(yp);
  u.s8[1] = cvt8(yp + 8);
  unsigned short* rp = ybf + ((size_t)n * K_ + k) * HW_ + s0 + sc;
  *(uint4*)rp       = u.q[0];
  *(uint4*)(rp + 8) = u.q[1];
#pragma unroll
  for (int j = 0; j < 16; ++j) tile[sc + j][k] = u.u16[j];
  __syncthreads();
  int s  = tid >> 2;
  int kc = (tid & 3) << 4;
  unsigned short* tp = ytr + ((size_t)n * HW_ + s0 + s) * K_ + kc;
  *(uint4*)tp       = *(const uint4*)&tile[s][kc];
  *(uint4*)(tp + 8) = *(const uint4*)&tile[s][kc + 8];
}

// K1: partial energies.  Block = (n, 16c, 1024s), 4 waves, 8 chunks of 128s,
// double-buffered LDS + counted vmcnt; gload_lds width-16 staging only.
// Wave w owns s-slice ss=w of each chunk and ALL 4 k-quadrants (4 accs):
// per chunk/wave = 2 A ds_reads + 4 cvt + 4 B ds_reads + 4 MFMA (A-frag
// read+converted ONCE, not 4x).  Waves hold disjoint s-partials -> 16 splits.
// Operand-swapped MFMA: A = y-frag (M=k), B = x-frag (N=c) -> float4 stores.
__global__ __launch_bounds__(256) void k_energy(const float* __restrict__ x,
                                                const unsigned short* __restrict__ ybf,
                                                float* __restrict__ partial){
  __shared__ char As[2][16 * 512];   // 2 x 8 KB:  16 c-rows x 128 f32
  __shared__ char Bs[2][64 * 256];   // 2 x 16 KB: 64 k-rows x 128 bf16
  const int bid = ((blockIdx.x & 7) << 7) | (blockIdx.x >> 3);  // XCD swizzle (1024%8==0)
  const int sp = bid & 3;
  const int ct = (bid >> 2) & 31;
  const int n  = bid >> 7;
  const int tid = threadIdx.x;
  const int w = tid >> 6, l = tid & 63;
  const int lo = l & 15, hi = l >> 4;
  const int c0 = ct << 4;
  const int sb = sp * SRANGE;

  // chunk-invariant per-lane source addresses (bytes) — staging unchanged
  const int ar0 = ((w << 1) + 0) * 2 + (l >> 5);
  const int ar1 = ((w << 1) + 1) * 2 + (l >> 5);
  const char* asrc0 = (const char*)(x + ((size_t)n * C_ + c0 + ar0) * HW_ + sb)
                      + ((16 * (l & 31)) ^ ((ar0 & 7) << 4));
  const char* asrc1 = (const char*)(x + ((size_t)n * C_ + c0 + ar1) * HW_ + sb)
                      + ((16 * (l & 31)) ^ ((ar1 & 7) << 4));
  const char* bsrc[4];
#pragma unroll
  for (int j = 0; j < 4; ++j){
    int kk = ((w << 2) + j) * 4 + (l >> 4);
    bsrc[j] = (const char*)(ybf + ((size_t)n * K_ + kk) * HW_ + sb)
              + ((16 * (l & 15)) ^ ((kk & 7) << 4));
  }

  floatx4 acc[4];
#pragma unroll
  for (int q = 0; q < 4; ++q) acc[q] = (floatx4){0.f, 0.f, 0.f, 0.f};
  const int aswz = (lo & 7) << 4;     // x-frag read swizzle (row = c = lo)
  const int bswz = aswz;              // y-row kk = q*16+lo -> (kk&7) == (lo&7)

#define STAGE(BUF, CH)                                                         \
  {                                                                            \
    gload16(asrc0 + (size_t)(CH) * (SCHUNK * 4), As[BUF] + ((w << 1) + 0) * 1024); \
    gload16(asrc1 + (size_t)(CH) * (SCHUNK * 4), As[BUF] + ((w << 1) + 1) * 1024); \
    _Pragma("unroll")                                                          \
    for (int j = 0; j < 4; ++j)                                                \
      gload16(bsrc[j] + (size_t)(CH) * (SCHUNK * 2), Bs[BUF] + ((w << 2) + j) * 1024); \
  }

  STAGE(0, 0)                       // prologue: chunk 0 in flight (6/wave)

#pragma unroll
  for (int ch = 0; ch < NCH; ++ch){
    const int cur = ch & 1;
    if (ch + 1 < NCH){
      STAGE(cur ^ 1, ch + 1)        // 6 more in flight (<=12)
      asm volatile("s_waitcnt vmcnt(6)" ::: "memory");   // chunk ch complete
    } else {
      asm volatile("s_waitcnt vmcnt(0)" ::: "memory");
    }
    __builtin_amdgcn_s_barrier();   // all waves' cur-chunk data in LDS
    __builtin_amdgcn_sched_barrier(0);
    {
      // wave's own s-slice ss = w (32 s of the 128-s chunk)
      int aoff = w * 128 + hi * 32;
      const char* ab = As[cur] + lo * 512;
      float4 a0f = *(const float4*)(ab + ((aoff     ) ^ aswz));
      float4 a1f = *(const float4*)(ab + ((aoff + 16) ^ aswz));
      union { unsigned u32[4]; short8 s; } af;
      asm("v_cvt_pk_bf16_f32 %0, %1, %2" : "=v"(af.u32[0]) : "v"(a0f.x), "v"(a0f.y));
      asm("v_cvt_pk_bf16_f32 %0, %1, %2" : "=v"(af.u32[1]) : "v"(a0f.z), "v"(a0f.w));
      asm("v_cvt_pk_bf16_f32 %0, %1, %2" : "=v"(af.u32[2]) : "v"(a1f.x), "v"(a1f.y));
      asm("v_cvt_pk_bf16_f32 %0, %1, %2" : "=v"(af.u32[3]) : "v"(a1f.z), "v"(a1f.w));
#pragma unroll
      for (int q = 0; q < 4; ++q){
        short8 b = *(const short8*)(Bs[cur] + (q * 16 + lo) * 256
                                    + ((w * 64 + hi * 16) ^ bswz));
        // swapped: A = y-frag (M=k), B = x-frag (N=c)
        acc[q] = __builtin_amdgcn_mfma_f32_16x16x32_bf16(b, af.s, acc[q], 0, 0, 0);
      }
    }
    __builtin_amdgcn_sched_barrier(0);   // pin ds_read/MFMA above the barrier
    __builtin_amdgcn_s_barrier();        // cur buffer free for overwrite
  }
#undef STAGE

  // D: col = lo -> c = c0+lo ; row = hi*4+r -> k = q*16 + hi*4 + r
  float* pp = partial + (((size_t)(sp * 4 + w) * N_ + n) * C_ + c0 + lo) * K_ + (hi << 2);
#pragma unroll
  for (int q = 0; q < 4; ++q)
    *(floatx4*)(pp + q * 16) = acc[q];
}

// K2: out = x + scale * softmax(-E) @ y.  Softmax fused in prologue (16-split
// reduce from partial, att tile in XOR-swizzled LDS).  Main loop swapped MFMA
// (A-frags straight from L2-hot ytr).  Epilogue re-coalesced: acc scattered
// into per-wave T[16][68] f32 LDS tile per 64-s group, then x-load/out-store
// emitted as 4 rows x 256 B contiguous per instruction.
__global__ __launch_bounds__(256) void k_out(const float* __restrict__ x,
                                             const float* __restrict__ partial,
                                             const unsigned short* __restrict__ ytr,
                                             const float* __restrict__ scale,
                                             float* __restrict__ out){
  __shared__ float xt[4][16][68];   // per-wave 16c x 64s transpose tile (17x16B rows)
  __shared__ char attl[16 * 128];   // 16 c-rows x 64 k bf16, XOR-swizzled
  int bid = ((blockIdx.x & 7) << 8) | (blockIdx.x >> 3);  // XCD swizzle (2048%8==0)
  int sb = bid & 7;
  int ct = (bid >> 3) & 31;
  int n  = bid >> 8;
  int tid = threadIdx.x;
  int w  = tid >> 6;
  int l  = tid & 63, lo = l & 15, hi = l >> 4;
  int c0 = ct << 4;
  int s0 = (sb << 9) + (w << 7);    // 512 per block, 128 per wave
  float sc = scale[0];

  // ---- fused softmax prologue: thread -> (c = tid>>4, 4 k's at 4*(tid&15)) ----
  {
    int c = tid >> 4, j = tid & 15;
    const float* pp = partial + ((size_t)n * C_ + c0 + c) * K_ + 4 * j;
    float e0 = 0.f, e1 = 0.f, e2 = 0.f, e3 = 0.f;
#pragma unroll
    for (int sp = 0; sp < NSPL; ++sp){
      float4 t = *(const float4*)(pp + (size_t)sp * (N_ * C_ * K_));
      e0 += t.x; e1 += t.y; e2 += t.z; e3 += t.w;
    }
    float m = fminf(fminf(e0, e1), fminf(e2, e3));
#pragma unroll
    for (int off = 8; off; off >>= 1) m = fminf(m, __shfl_xor(m, off, 16));
    float p0 = __expf(m - e0), p1 = __expf(m - e1);
    float p2 = __expf(m - e2), p3 = __expf(m - e3);
    float s = p0 + p1 + p2 + p3;
#pragma unroll
    for (int off = 8; off; off >>= 1) s += __shfl_xor(s, off, 16);
    float inv = 1.f / s;
    unsigned d0, d1;
    asm("v_cvt_pk_bf16_f32 %0, %1, %2" : "=v"(d0) : "v"(p0 * inv), "v"(p1 * inv));
    asm("v_cvt_pk_bf16_f32 %0, %1, %2" : "=v"(d1) : "v"(p2 * inv), "v"(p3 * inv));
    uint2 dd; dd.x = d0; dd.y = d1;
    *(uint2*)(attl + c * 128 + ((8 * j) ^ ((c & 7) << 4))) = dd;
  }
  __syncthreads();

  // att fragments (B operand: col = lo -> c, per-lane k = hi*8.. / +32)
  short8 batt0 = *(const short8*)(attl + lo * 128 + ((     hi * 16) ^ ((lo & 7) << 4)));
  short8 batt1 = *(const short8*)(attl + lo * 128 + ((64 + hi * 16) ^ ((lo & 7) << 4)));

  const unsigned short* yb = ytr + (size_t)n * HW_ * K_;
  float (*T)[68] = xt[w];

#pragma unroll
  for (int g = 0; g < 2; ++g){
    int sg = s0 + g * 64;
    // ---- compute 16c x 64s, scatter into T ----
#pragma unroll
    for (int t = 0; t < 4; ++t){
      const unsigned short* ap = yb + (size_t)(sg + t * 16 + lo) * K_ + hi * 8;
      short8 a0 = *(const short8*)(ap);        // A: row = lo -> s, k = hi*8..
      short8 a1 = *(const short8*)(ap + 32);   // k = 32 + hi*8..
      floatx4 acc = {0.f, 0.f, 0.f, 0.f};
      acc = __builtin_amdgcn_mfma_f32_16x16x32_bf16(a0, batt0, acc, 0, 0, 0);
      acc = __builtin_amdgcn_mfma_f32_16x16x32_bf16(a1, batt1, acc, 0, 0, 0);
      // D: col = lo -> c, row = hi*4+r -> s_local = t*16 + hi*4 + r
      *(floatx4*)&T[lo][t * 16 + (hi << 2)] = acc;   // 16B-aligned b128 write
    }
    // ---- emit 4 rows x 256B contiguous per instruction (wave-internal DS order) ----
#pragma unroll
    for (int rg = 0; rg < 4; ++rg){
      int c = (rg << 2) + hi;
      float4 v = *(const float4*)&T[c][lo << 2];
      size_t off = ((size_t)n * C_ + c0 + c) * HW_ + sg + (lo << 2);
      float4 xv = *(const float4*)(x + off);
      float4 o;
      o.x = xv.x + sc * v.x; o.y = xv.y + sc * v.y;
      o.z = xv.z + sc * v.z; o.w = xv.w + sc * v.w;
      *(float4*)(out + off) = o;
    }
  }
}

extern "C" void kernel_launch(void* const* d_in, const int* in_sizes, int n_in,
                              void* d_out, int out_size, void* d_ws, size_t ws_size,
                              hipStream_t stream){
  const float* x     = (const float*)d_in[0];
  const float* y     = (const float*)d_in[1];
  const float* scale = (const float*)d_in[2];
  float* out = (float*)d_out;

  // ws layout (24 MiB total):
  //   partial : NSPL * N*C*K f32  = 16 MiB  @ 0   ([spl][n][c][k])
  //   ybf     : N*K*HW bf16       = 4 MiB   @ 16 MiB
  //   ytr     : N*HW*K bf16       = 4 MiB   @ 20 MiB
  char* ws = (char*)d_ws;
  float*          partial = (float*)(ws);
  unsigned short* ybf     = (unsigned short*)(ws + (16u<<20));
  unsigned short* ytr     = (unsigned short*)(ws + (20u<<20));

  k_prep   <<<N_ * (HW_/64),    256, 0, stream>>>(y, ybf, ytr);
  k_energy <<<N_ * 32 * SPLITS, 256, 0, stream>>>(x, ybf, partial);
  k_out    <<<N_ * 32 * 8,      256, 0, stream>>>(x, partial, ytr, scale, out);
}

// Round 11
// 51.999 us; speedup vs baseline: 1.1482x; 1.0489x over previous
//
#include <hip/hip_runtime.h>

// CCAMDec: out = x + scale * softmax(max_k(E)-E) @ y,  E = x·yᵀ over HW
// N=8, C=512, K=64, HW=4096. softmax(max-E) == softmax(-E) (shift invariance).
#define N_ 8
#define C_ 512
#define K_ 64
#define HW_ 4096
#define SCHUNK 128              // s per staged chunk in fused energy phase
#define NCH 32                  // chunks (full s = 4096)

typedef __attribute__((ext_vector_type(8))) short short8;   // 8 bf16 (4 VGPRs) MFMA A/B frag
typedef __attribute__((ext_vector_type(4))) float floatx4;  // MFMA C/D frag

// 8 f32 -> 8 bf16 via hardware v_cvt_pk_bf16_f32 (RNE, 1 instr / 2 elems)
__device__ __forceinline__ short8 cvt8(const float* __restrict__ p){
  float4 u = *(const float4*)p;
  float4 w = *(const float4*)(p + 4);
  union { unsigned u32[4]; short8 s; } r;
  asm("v_cvt_pk_bf16_f32 %0, %1, %2" : "=v"(r.u32[0]) : "v"(u.x), "v"(u.y));
  asm("v_cvt_pk_bf16_f32 %0, %1, %2" : "=v"(r.u32[1]) : "v"(u.z), "v"(u.w));
  asm("v_cvt_pk_bf16_f32 %0, %1, %2" : "=v"(r.u32[2]) : "v"(w.x), "v"(w.y));
  asm("v_cvt_pk_bf16_f32 %0, %1, %2" : "=v"(r.u32[3]) : "v"(w.z), "v"(w.w));
  return r.s;
}

// async global -> LDS, 16 B/lane (1 KB/wave), zero VGPR cost
__device__ __forceinline__ void gload16(const void* g, void* l){
  __builtin_amdgcn_global_load_lds(
      (const __attribute__((address_space(1))) void*)g,
      (__attribute__((address_space(3))) void*)l, 16, 0, 0);
}

// K0: y (f32, [n][k][s]) -> ybf (bf16 row-major [n][k][s]) and ytr (bf16 [n][s][k])
__global__ __launch_bounds__(256) void k_prep(const float* __restrict__ y,
                                              unsigned short* __restrict__ ybf,
                                              unsigned short* __restrict__ ytr){
  __shared__ unsigned short tile[64][72];
  int n  = blockIdx.x >> 6;                 // 64 s-tiles per batch
  int s0 = (blockIdx.x & 63) << 6;
  int tid = threadIdx.x;
  int k  = tid >> 2;
  int sc = (tid & 3) << 4;
  const float* yp = y + ((size_t)n * K_ + k) * HW_ + s0 + sc;
  union { unsigned short u16[16]; short8 s8[2]; uint4 q[2]; } u;
  u.s8[0] = cvt8(yp);
  u.s8[1] = cvt8(yp + 8);
  unsigned short* rp = ybf + ((size_t)n * K_ + k) * HW_ + s0 + sc;
  *(uint4*)rp       = u.q[0];
  *(uint4*)(rp + 8) = u.q[1];
#pragma unroll
  for (int j = 0; j < 16; ++j) tile[sc + j][k] = u.u16[j];
  __syncthreads();
  int s  = tid >> 2;
  int kc = (tid & 3) << 4;
  unsigned short* tp = ytr + ((size_t)n * HW_ + s0 + s) * K_ + kc;
  *(uint4*)tp       = *(const uint4*)&tile[s][kc];
  *(uint4*)(tp + 8) = *(const uint4*)&tile[s][kc + 8];
}

// K1: FUSED energy + softmax + PV + residual.  Grid 256 (1 block/CU),
// 512 thr (8 waves).  Block = (n, 16c) over FULL s.
//  Phase E: 32 chunks of 128 s, 4-buffer 3-deep gload_lds pipeline
//           (vmcnt(9) counted, never 0 mid-loop).  Wave (h=w>>2, q=w&3):
//           s-half h, k-quadrant q; swapped MFMA (A=y, B=x) -> E col=c,row=k.
//  Phase S: reduce Els[2][16][64] over h, softmax(-E), att -> swizzled LDS.
//  Phase P: wave w owns s in [w*512,(w+1)*512); 8 groups of 64 s; explicit
//           2-deep register pipeline (named sets, rule #20); acc -> T[16][68]
//           transpose -> 256B-contiguous x-load/out-store.  No partial buffer.
__global__ __launch_bounds__(512, 1) void k_fused(const float* __restrict__ x,
                                                  const unsigned short* __restrict__ ybf,
                                                  const unsigned short* __restrict__ ytr,
                                                  const float* __restrict__ scale,
                                                  float* __restrict__ out){
  __shared__ char As[4][8192];      // 32 KB: 16 c-rows x 128 f32 per buf
  __shared__ char Bs[4][16384];     // 64 KB: 64 k-rows x 128 bf16 per buf
  __shared__ float Els[2][16][64];  // 8 KB  E partials per s-half
  __shared__ char attl[2048];       // att 16c x 64k bf16, XOR-swizzled
  __shared__ float T[8][16][68];    // 34 KB per-wave PV transpose tiles

  const int bid = ((blockIdx.x & 7) << 5) | (blockIdx.x >> 3);  // XCD swizzle (256%8==0)
  const int ct = bid & 31, n = bid >> 5;
  const int tid = threadIdx.x;
  const int w = tid >> 6, l = tid & 63;
  const int lo = l & 15, hi = l >> 4;
  const int h = w >> 2, q = w & 3;
  const int c0 = ct << 4;

  float sc = scale[0];
  asm volatile("" :: "v"(sc));      // force completion: keep vmcnt counts clean

  // ---- Phase E: staging addresses (chunk-invariant, pre-swizzled source) ----
  const int ar = (w << 1) + (l >> 5);            // A: wave w covers c-rows 2w,2w+1
  const char* asrc = (const char*)(x + ((size_t)n * C_ + c0 + ar) * HW_)
                     + ((16 * (l & 31)) ^ ((ar & 7) << 4));
  const int kb0 = ((w << 1) + 0) * 4 + (l >> 4); // B: wave w covers k-rows 8w..8w+7
  const int kb1 = ((w << 1) + 1) * 4 + (l >> 4);
  const char* bsrc0 = (const char*)(ybf + ((size_t)n * K_ + kb0) * HW_)
                      + ((16 * (l & 15)) ^ ((kb0 & 7) << 4));
  const char* bsrc1 = (const char*)(ybf + ((size_t)n * K_ + kb1) * HW_)
                      + ((16 * (l & 15)) ^ ((kb1 & 7) << 4));

  floatx4 acc = {0.f, 0.f, 0.f, 0.f};
  const int aswz = (lo & 7) << 4;     // read swizzle; B row q*16+lo has same &7
  const int brow = (q << 4) + lo;

#define STAGE(BUF, CH)                                                          \
  {                                                                             \
    gload16(asrc  + (size_t)(CH) * (SCHUNK * 4), As[BUF] + (w << 10));          \
    gload16(bsrc0 + (size_t)(CH) * (SCHUNK * 2), Bs[BUF] + ((w << 1) << 10));   \
    gload16(bsrc1 + (size_t)(CH) * (SCHUNK * 2), Bs[BUF] + ((((w << 1) | 1)) << 10)); \
  }

  STAGE(0, 0) STAGE(1, 1) STAGE(2, 2)   // 9 loads/wave in flight

#pragma unroll
  for (int ch = 0; ch < NCH; ++ch){
    const int cur = ch & 3;
    if (ch + 3 < NCH){
      STAGE((ch + 3) & 3, ch + 3)
      asm volatile("s_waitcnt vmcnt(9)" ::: "memory");   // chunk ch complete
    } else if (ch + 2 < NCH){
      asm volatile("s_waitcnt vmcnt(6)" ::: "memory");
    } else if (ch + 1 < NCH){
      asm volatile("s_waitcnt vmcnt(3)" ::: "memory");
    } else {
      asm volatile("s_waitcnt vmcnt(0)" ::: "memory");
    }
    __builtin_amdgcn_s_barrier();
    __builtin_amdgcn_sched_barrier(0);
#pragma unroll
    for (int ss = 0; ss < 2; ++ss){
      int ao = (h << 8) + (ss << 7) + (hi << 5);     // s = h*64 + ss*32 + hi*8 (f32 bytes)
      const char* ab = As[cur] + (lo << 9);
      float4 a0f = *(const float4*)(ab + ((ao     ) ^ aswz));
      float4 a1f = *(const float4*)(ab + ((ao + 16) ^ aswz));
      union { unsigned u32[4]; short8 s; } af;
      asm("v_cvt_pk_bf16_f32 %0, %1, %2" : "=v"(af.u32[0]) : "v"(a0f.x), "v"(a0f.y));
      asm("v_cvt_pk_bf16_f32 %0, %1, %2" : "=v"(af.u32[1]) : "v"(a0f.z), "v"(a0f.w));
      asm("v_cvt_pk_bf16_f32 %0, %1, %2" : "=v"(af.u32[2]) : "v"(a1f.x), "v"(a1f.y));
      asm("v_cvt_pk_bf16_f32 %0, %1, %2" : "=v"(af.u32[3]) : "v"(a1f.z), "v"(a1f.w));
      int bo = (h << 7) + (ss << 6) + (hi << 4);     // same s in bf16 bytes
      short8 b = *(const short8*)(Bs[cur] + brow * 256 + (bo ^ aswz));
      // swapped: A = y-frag (M=k), B = x-frag (N=c) -> D col=lo->c, row->k
      acc = __builtin_amdgcn_mfma_f32_16x16x32_bf16(b, af.s, acc, 0, 0, 0);
    }
    __builtin_amdgcn_sched_barrier(0);
    __builtin_amdgcn_s_barrier();
  }
#undef STAGE

  // E partial: [h][c=lo][k = q*16 + hi*4 + r]
  *(floatx4*)&Els[h][lo][(q << 4) + (hi << 2)] = acc;
  __syncthreads();

  // ---- Phase S: softmax(-E) over k, att -> swizzled LDS (256 threads) ----
  if (tid < 256){
    int c = tid >> 4, j = tid & 15;
    float4 t0 = *(const float4*)&Els[0][c][4 * j];
    float4 t1 = *(const float4*)&Els[1][c][4 * j];
    float e0 = t0.x + t1.x, e1 = t0.y + t1.y, e2 = t0.z + t1.z, e3 = t0.w + t1.w;
    float m = fminf(fminf(e0, e1), fminf(e2, e3));
#pragma unroll
    for (int off = 8; off; off >>= 1) m = fminf(m, __shfl_xor(m, off, 16));
    float p0 = __expf(m - e0), p1 = __expf(m - e1);
    float p2 = __expf(m - e2), p3 = __expf(m - e3);
    float s = p0 + p1 + p2 + p3;
#pragma unroll
    for (int off = 8; off; off >>= 1) s += __shfl_xor(s, off, 16);
    float inv = 1.f / s;
    unsigned d0, d1;
    asm("v_cvt_pk_bf16_f32 %0, %1, %2" : "=v"(d0) : "v"(p0 * inv), "v"(p1 * inv));
    asm("v_cvt_pk_bf16_f32 %0, %1, %2" : "=v"(d1) : "v"(p2 * inv), "v"(p3 * inv));
    uint2 dd; dd.x = d0; dd.y = d1;
    *(uint2*)(attl + c * 128 + ((8 * j) ^ ((c & 7) << 4))) = dd;
  }
  __syncthreads();

  // ---- Phase P: PV + residual.  Wave w: s in [w*512, (w+1)*512) ----
  short8 batt0 = *(const short8*)(attl + lo * 128 + ((     hi * 16) ^ ((lo & 7) << 4)));
  short8 batt1 = *(const short8*)(attl + lo * 128 + ((64 + hi * 16) ^ ((lo & 7) << 4)));
  const unsigned short* ybn = ytr + (size_t)n * HW_ * K_;
  const int sW = w << 9;
  float (*Tw)[68] = T[w];
  size_t xb[4];
#pragma unroll
  for (int rg = 0; rg < 4; ++rg)
    xb[rg] = ((size_t)n * C_ + c0 + (rg << 2) + hi) * HW_ + sW + (lo << 2);

  short8 aA[8]; float4 xA[4];
  short8 aB[8]; float4 xB[4];

#define PVLOAD(G, AV, XV)                                                      \
  {                                                                            \
    int sg = sW + (G) * 64;                                                    \
    _Pragma("unroll")                                                          \
    for (int t = 0; t < 4; ++t){                                               \
      const unsigned short* ap = ybn + (size_t)(sg + t * 16 + lo) * K_ + (hi << 3); \
      AV[2 * t]     = *(const short8*)(ap);                                    \
      AV[2 * t + 1] = *(const short8*)(ap + 32);                               \
    }                                                                          \
    _Pragma("unroll")                                                          \
    for (int rg = 0; rg < 4; ++rg)                                             \
      XV[rg] = *(const float4*)(x + xb[rg] + (G) * 64);                        \
  }

#define PVCOMP(G, AV, XV)                                                      \
  {                                                                            \
    _Pragma("unroll")                                                          \
    for (int t = 0; t < 4; ++t){                                               \
      floatx4 a2 = {0.f, 0.f, 0.f, 0.f};                                       \
      a2 = __builtin_amdgcn_mfma_f32_16x16x32_bf16(AV[2 * t],     batt0, a2, 0, 0, 0); \
      a2 = __builtin_amdgcn_mfma_f32_16x16x32_bf16(AV[2 * t + 1], batt1, a2, 0, 0, 0); \
      *(floatx4*)&Tw[lo][t * 16 + (hi << 2)] = a2;   /* D: col=lo->c, row->s */ \
    }                                                                          \
    _Pragma("unroll")                                                          \
    for (int rg = 0; rg < 4; ++rg){                                            \
      float4 v  = *(const float4*)&Tw[(rg << 2) + hi][lo << 2];                \
      float4 xv = XV[rg];                                                      \
      float4 o;                                                                \
      o.x = xv.x + sc * v.x; o.y = xv.y + sc * v.y;                            \
      o.z = xv.z + sc * v.z; o.w = xv.w + sc * v.w;                            \
      *(float4*)(out + xb[rg] + (G) * 64) = o;                                 \
    }                                                                          \
  }

  PVLOAD(0, aA, xA)
#pragma unroll
  for (int g = 0; g < 8; g += 2){
    PVLOAD(g + 1, aB, xB)
    PVCOMP(g, aA, xA)
    if (g + 2 < 8) PVLOAD(g + 2, aA, xA)
    PVCOMP(g + 1, aB, xB)
  }
#undef PVLOAD
#undef PVCOMP
}

extern "C" void kernel_launch(void* const* d_in, const int* in_sizes, int n_in,
                              void* d_out, int out_size, void* d_ws, size_t ws_size,
                              hipStream_t stream){
  const float* x     = (const float*)d_in[0];
  const float* y     = (const float*)d_in[1];
  const float* scale = (const float*)d_in[2];
  float* out = (float*)d_out;

  // ws layout (8 MiB total):
  //   ybf : N*K*HW bf16 = 4 MiB  @ 0
  //   ytr : N*HW*K bf16 = 4 MiB  @ 4 MiB
  char* ws = (char*)d_ws;
  unsigned short* ybf = (unsigned short*)(ws);
  unsigned short* ytr = (unsigned short*)(ws + (4u<<20));

  k_prep  <<<N_ * (HW_/64), 256, 0, stream>>>(y, ybf, ytr);
  k_fused <<<N_ * 32,       512, 0, stream>>>(x, ybf, ytr, scale, out);
}